// Round 1
// baseline (924.664 us; speedup 1.0000x reference)
//
#include <hip/hip_runtime.h>
#include <math.h>

#define NPTS 4096
#define NB 2
#define K_TOTAL 16
#define BLOCK 256
#define ROWS_PER_CHUNK 16

// ws layout (floats):
//  [0..31]              sched: 16 x {eps, w}
//  [32 .. 32+32768)     pot buffer 0: 4 pots x 2 batches x 4096
//  [.. +32768)          pot buffer 1
#define SCHED_OFF 0
#define POT0_OFF 32
#define POT_SZ (4 * NB * NPTS)

#if __has_builtin(__builtin_amdgcn_exp2f)
#define EXP2F __builtin_amdgcn_exp2f
#else
#define EXP2F exp2f
#endif
#if __has_builtin(__builtin_amdgcn_logf)
#define LOG2F __builtin_amdgcn_logf
#else
#define LOG2F log2f
#endif
#if __has_builtin(__builtin_amdgcn_sqrtf)
#define FSQRTF __builtin_amdgcn_sqrtf
#else
#define FSQRTF sqrtf
#endif

// ---------------------------------------------------------------------------
// Kernel A: zero pot buffer 0, compute diameter (f32, matching numpy), build
// the eps schedule (f64, matching np.arange/np.exp), fill unused slots w=1.
// ---------------------------------------------------------------------------
__global__ __launch_bounds__(BLOCK) void k_schedule(
    const float2* __restrict__ x, const float2* __restrict__ y, float* ws)
{
  const int tid = threadIdx.x;
  float* pot0 = ws + POT0_OFF;
  for (int i = tid; i < POT_SZ; i += BLOCK) pot0[i] = 0.0f;

  float mnx = 1e30f, mny = 1e30f, mxx = -1e30f, mxy = -1e30f;
  for (int i = tid; i < NB * NPTS; i += BLOCK) {
    float2 p = x[i];
    mnx = fminf(mnx, p.x); mxx = fmaxf(mxx, p.x);
    mny = fminf(mny, p.y); mxy = fmaxf(mxy, p.y);
    float2 q = y[i];
    mnx = fminf(mnx, q.x); mxx = fmaxf(mxx, q.x);
    mny = fminf(mny, q.y); mxy = fmaxf(mxy, q.y);
  }
  for (int o = 32; o; o >>= 1) {
    mnx = fminf(mnx, __shfl_xor(mnx, o, 64));
    mxx = fmaxf(mxx, __shfl_xor(mxx, o, 64));
    mny = fminf(mny, __shfl_xor(mny, o, 64));
    mxy = fmaxf(mxy, __shfl_xor(mxy, o, 64));
  }
  __shared__ float r[4][4];
  const int wave = tid >> 6, lane = tid & 63;
  if (lane == 0) { r[0][wave] = mnx; r[1][wave] = mxx; r[2][wave] = mny; r[3][wave] = mxy; }
  __syncthreads();
  if (tid == 0) {
    mnx = fminf(fminf(r[0][0], r[0][1]), fminf(r[0][2], r[0][3]));
    mxx = fmaxf(fmaxf(r[1][0], r[1][1]), fmaxf(r[1][2], r[1][3]));
    mny = fminf(fminf(r[2][0], r[2][1]), fminf(r[2][2], r[2][3]));
    mxy = fmaxf(fmaxf(r[3][0], r[3][1]), fmaxf(r[3][2], r[3][3]));
    float rx = mxx - mnx, ry = mxy - mny;
    float dia = sqrtf(rx * rx + ry * ry);  // f32, matches np.linalg.norm(float32)

    double a = log((double)dia);
    double stop = log(0.05);
    double stp = log(0.5);
    int cnt = (int)ceil((stop - a) / stp);  // np.arange length
    if (cnt < 0) cnt = 0;
    if (cnt > K_TOTAL - 4) cnt = K_TOTAL - 4;

    float* sch = ws + SCHED_OFF;
    // slot 0: init at eps = diameter, direct assign (w=0)
    sch[0] = dia; sch[1] = 0.0f;
    // loop slots: eps_list = [dia] + exp(a + k*stp), k<cnt + [0.05], all w=0.5
    sch[2] = dia; sch[3] = 0.5f;
    for (int k = 0; k < cnt; k++) {
      sch[2 * (2 + k)] = (float)exp(a + (double)k * stp);
      sch[2 * (2 + k) + 1] = 0.5f;
    }
    sch[2 * (2 + cnt)] = 0.05f; sch[2 * (2 + cnt) + 1] = 0.5f;
    // padding: w=1 => f_new = f_old (exact no-op, same work each step)
    for (int s = 3 + cnt; s < K_TOTAL - 1; s++) { sch[2 * s] = 0.05f; sch[2 * s + 1] = 1.0f; }
    // last slot: final extrapolation at eps = blur, direct assign
    sch[2 * (K_TOTAL - 1)] = 0.05f; sch[2 * (K_TOTAL - 1) + 1] = 0.0f;
  }
}

// ---------------------------------------------------------------------------
// Kernel B: one annealing step = 4 independent softmins (jobs), all reading
// pot_old, writing pot_new = w*old + (1-w)*softmin.
// job0: f_ba rows=x cols=y h=g_ab | job1: g_ab rows=y cols=x h=f_ba
// job2: f_aa rows=x cols=x h=f_aa | job3: g_bb rows=y cols=y h=g_bb
// ---------------------------------------------------------------------------
__global__ __launch_bounds__(BLOCK) void k_softmin(
    const float2* __restrict__ xpts, const float2* __restrict__ ypts,
    const float* __restrict__ ws_sched,
    const float* __restrict__ pot_old, float* __restrict__ pot_new, int stepi)
{
  __shared__ float2 ys[NPTS];   // staged column points
  __shared__ float hs[NPTS];    // staged (h - M)*log2e
  __shared__ float redm[4];

  const int tid = threadIdx.x;
  const int lane = tid & 63, wave = tid >> 6;
  const int chunk = blockIdx.x, b = blockIdx.y, job = blockIdx.z;

  const float eps = ws_sched[2 * stepi];
  const float wmix = ws_sched[2 * stepi + 1];
  const float inv_eps = 1.0f / eps;
  const float LOG2E = 1.4426950408889634f;
  const float ce = inv_eps * LOG2E;
  const float base = -8.31776616671934f;  // -log(4096), N==M

  const float2* rows = (job == 1 || job == 3) ? ypts : xpts;
  const float2* cols = (job == 0 || job == 3) ? ypts : xpts;
  const int hk = (job == 0) ? 1 : (job == 1) ? 0 : job;

  const float* hsrc = pot_old + (hk * NB + b) * NPTS;
  const float* fold_src = pot_old + (job * NB + b) * NPTS;
  float* fdst = pot_new + (job * NB + b) * NPTS;
  const float2* colp = cols + b * NPTS;
  const float2* rowp = rows + b * NPTS;

  // stage columns + h into LDS, track max(h)
  float lmax = -1e30f;
  for (int j = tid; j < NPTS; j += BLOCK) {
    float2 c = colp[j];
    float h = fmaf(hsrc[j], inv_eps, base);
    ys[j] = c;
    hs[j] = h;
    lmax = fmaxf(lmax, h);
  }
  for (int o = 32; o; o >>= 1) lmax = fmaxf(lmax, __shfl_xor(lmax, o, 64));
  if (lane == 0) redm[wave] = lmax;
  __syncthreads();
  const float M = fmaxf(fmaxf(redm[0], redm[1]), fmaxf(redm[2], redm[3]));
  for (int j = tid; j < NPTS; j += BLOCK) hs[j] = (hs[j] - M) * LOG2E;  // own elems, RAW same-thread
  __syncthreads();

  const int row0 = chunk * ROWS_PER_CHUNK + wave * 4;
  for (int q = 0; q < 4; q++) {
    const int rr = row0 + q;
    const float2 xi = rowp[rr];
    float s = 0.0f;
#pragma unroll 8
    for (int jj = 0; jj < NPTS / 64; jj++) {
      const int j = (jj << 6) | lane;
      float2 yj = ys[j];
      float hh = hs[j];
      float dx = xi.x - yj.x;
      float dy = xi.y - yj.y;
      float d2 = fmaf(dx, dx, dy * dy);
      d2 = fmaxf(d2, 1e-12f);
      float c = FSQRTF(d2);
      float arg = fmaf(c, -ce, hh);  // (h_j - M)*log2e - c/eps*log2e, <= 0
      s += EXP2F(arg);
    }
    for (int o = 32; o; o >>= 1) s += __shfl_xor(s, o, 64);
    if (lane == 0) {
      s = fmaxf(s, 1e-37f);  // insurance vs full-row underflow -> -inf
      float ft = -eps * fmaf(0.69314718055994531f, LOG2F(s), M);
      float fo = fold_src[rr];
      float fn = (wmix >= 1.0f) ? fo : fmaf(wmix, fo, (1.0f - wmix) * ft);
      fdst[rr] = fn;
    }
  }
}

// ---------------------------------------------------------------------------
// Kernel C: out = mean_b [ (1/N) sum(f_ba - f_aa) + (1/M) sum(g_ab - g_bb) ]
// ---------------------------------------------------------------------------
__global__ __launch_bounds__(BLOCK) void k_reduce(
    const float* __restrict__ pot, float* __restrict__ out)
{
  const int tid = threadIdx.x;
  double acc = 0.0;
  for (int i = tid; i < POT_SZ; i += BLOCK) {
    double v = (double)pot[i];
    acc += (i < 2 * NB * NPTS) ? v : -v;  // +f_ba +g_ab -f_aa -g_bb
  }
  for (int o = 32; o; o >>= 1) acc += __shfl_xor(acc, o, 64);
  __shared__ double rd[4];
  const int wave = tid >> 6, lane = tid & 63;
  if (lane == 0) rd[wave] = acc;
  __syncthreads();
  if (tid == 0) out[0] = (float)((rd[0] + rd[1] + rd[2] + rd[3]) / (double)(NB * NPTS));
}

extern "C" void kernel_launch(void* const* d_in, const int* in_sizes, int n_in,
                              void* d_out, int out_size, void* d_ws, size_t ws_size,
                              hipStream_t stream)
{
  const float2* x = (const float2*)d_in[0];  // pre (2,4096,2)
  const float2* y = (const float2*)d_in[1];  // gt  (2,4096,2)
  float* ws = (float*)d_ws;
  float* sched = ws + SCHED_OFF;
  float* pot0 = ws + POT0_OFF;
  float* pot1 = pot0 + POT_SZ;

  k_schedule<<<1, BLOCK, 0, stream>>>(x, y, ws);

  dim3 grid(NPTS / ROWS_PER_CHUNK, NB, 4);
  for (int s = 0; s < K_TOTAL; s++) {
    const float* po = (s & 1) ? pot1 : pot0;
    float* pn = (s & 1) ? pot0 : pot1;
    k_softmin<<<grid, BLOCK, 0, stream>>>(x, y, sched, po, pn, s);
  }
  // K_TOTAL even -> final potentials land in pot0
  k_reduce<<<1, BLOCK, 0, stream>>>(pot0, (float*)d_out);
}

// Round 2
// 645.262 us; speedup vs baseline: 1.4330x; 1.4330x over previous
//
#include <hip/hip_runtime.h>
#include <math.h>

#define NPTS 4096
#define NB 2
#define K_TOTAL 12
#define BLOCK 256
#define ROWS_PER_CHUNK 16

// ws layout (floats):
//  [0..2*K_TOTAL)       sched: K_TOTAL x {eps, w}
//  [32 .. 32+32768)     pot buffer 0: 4 pots x 2 batches x 4096
//  [.. +32768)          pot buffer 1
#define SCHED_OFF 0
#define POT0_OFF 32
#define POT_SZ (4 * NB * NPTS)

#if __has_builtin(__builtin_amdgcn_exp2f)
#define EXP2F __builtin_amdgcn_exp2f
#else
#define EXP2F exp2f
#endif
#if __has_builtin(__builtin_amdgcn_logf)
#define LOG2F __builtin_amdgcn_logf
#else
#define LOG2F log2f
#endif
#if __has_builtin(__builtin_amdgcn_sqrtf)
#define FSQRTF __builtin_amdgcn_sqrtf
#else
#define FSQRTF sqrtf
#endif

// ---------------------------------------------------------------------------
// Kernel A: zero pot buffer 0, compute diameter (f32, matching numpy), build
// the eps schedule (f64, matching np.arange/np.exp), fill unused slots w=1.
// ---------------------------------------------------------------------------
__global__ __launch_bounds__(BLOCK) void k_schedule(
    const float2* __restrict__ x, const float2* __restrict__ y, float* ws)
{
  const int tid = threadIdx.x;
  float* pot0 = ws + POT0_OFF;
  for (int i = tid; i < POT_SZ; i += BLOCK) pot0[i] = 0.0f;

  float mnx = 1e30f, mny = 1e30f, mxx = -1e30f, mxy = -1e30f;
  for (int i = tid; i < NB * NPTS; i += BLOCK) {
    float2 p = x[i];
    mnx = fminf(mnx, p.x); mxx = fmaxf(mxx, p.x);
    mny = fminf(mny, p.y); mxy = fmaxf(mxy, p.y);
    float2 q = y[i];
    mnx = fminf(mnx, q.x); mxx = fmaxf(mxx, q.x);
    mny = fminf(mny, q.y); mxy = fmaxf(mxy, q.y);
  }
  for (int o = 32; o; o >>= 1) {
    mnx = fminf(mnx, __shfl_xor(mnx, o, 64));
    mxx = fmaxf(mxx, __shfl_xor(mxx, o, 64));
    mny = fminf(mny, __shfl_xor(mny, o, 64));
    mxy = fmaxf(mxy, __shfl_xor(mxy, o, 64));
  }
  __shared__ float r[4][4];
  const int wave = tid >> 6, lane = tid & 63;
  if (lane == 0) { r[0][wave] = mnx; r[1][wave] = mxx; r[2][wave] = mny; r[3][wave] = mxy; }
  __syncthreads();
  if (tid == 0) {
    mnx = fminf(fminf(r[0][0], r[0][1]), fminf(r[0][2], r[0][3]));
    mxx = fmaxf(fmaxf(r[1][0], r[1][1]), fmaxf(r[1][2], r[1][3]));
    mny = fminf(fminf(r[2][0], r[2][1]), fminf(r[2][2], r[2][3]));
    mxy = fmaxf(fmaxf(r[3][0], r[3][1]), fmaxf(r[3][2], r[3][3]));
    float rx = mxx - mnx, ry = mxy - mny;
    float dia = sqrtf(rx * rx + ry * ry);  // f32, matches np.linalg.norm(float32)

    double a = log((double)dia);
    double stop = log(0.05);
    double stp = log(0.5);
    int cnt = (int)ceil((stop - a) / stp);  // np.arange length (data: cnt==8)
    if (cnt < 0) cnt = 0;
    if (cnt > K_TOTAL - 4) cnt = K_TOTAL - 4;

    float* sch = ws + SCHED_OFF;
    // slot 0: init at eps = diameter, direct assign (w=0)
    sch[0] = dia; sch[1] = 0.0f;
    // loop slots: eps_list = [dia] + exp(a + k*stp), k<cnt + [0.05], all w=0.5
    sch[2] = dia; sch[3] = 0.5f;
    for (int k = 0; k < cnt; k++) {
      sch[2 * (2 + k)] = (float)exp(a + (double)k * stp);
      sch[2 * (2 + k) + 1] = 0.5f;
    }
    sch[2 * (2 + cnt)] = 0.05f; sch[2 * (2 + cnt) + 1] = 0.5f;
    // padding (only if cnt < 8): w=1 => f_new = f_old (exact no-op)
    for (int s = 3 + cnt; s < K_TOTAL - 1; s++) { sch[2 * s] = 0.05f; sch[2 * s + 1] = 1.0f; }
    // last slot: final extrapolation at eps = blur, direct assign
    sch[2 * (K_TOTAL - 1)] = 0.05f; sch[2 * (K_TOTAL - 1) + 1] = 0.0f;
  }
}

// ---------------------------------------------------------------------------
// Kernel B: one annealing step = 4 independent softmins (jobs), all reading
// pot_old, writing pot_new = w*old + (1-w)*softmin.
// job0: f_ba rows=x cols=y h=g_ab | job1: g_ab rows=y cols=x h=f_ba
// job2: f_aa rows=x cols=x h=f_aa | job3: g_bb rows=y cols=y h=g_bb
// Each wave sweeps the 4096 columns ONCE with 4 row-accumulators (ILP-4,
// LDS traffic amortized 4x; transcendental pipe gets 4 independent chains).
// ---------------------------------------------------------------------------
__global__ __launch_bounds__(BLOCK) void k_softmin(
    const float2* __restrict__ xpts, const float2* __restrict__ ypts,
    const float* __restrict__ ws_sched,
    const float* __restrict__ pot_old, float* __restrict__ pot_new, int stepi)
{
  __shared__ float2 ys[NPTS];   // staged column points
  __shared__ float hs[NPTS];    // staged (h - M)*log2e
  __shared__ float redm[4];

  const int tid = threadIdx.x;
  const int lane = tid & 63, wave = tid >> 6;
  const int chunk = blockIdx.x, b = blockIdx.y, job = blockIdx.z;

  const float eps = ws_sched[2 * stepi];
  const float wmix = ws_sched[2 * stepi + 1];
  const float inv_eps = 1.0f / eps;
  const float LOG2E = 1.4426950408889634f;
  const float ce = inv_eps * LOG2E;
  const float base = -8.31776616671934f;  // -log(4096), N==M

  const float2* rows = (job == 1 || job == 3) ? ypts : xpts;
  const float2* cols = (job == 0 || job == 3) ? ypts : xpts;
  const int hk = (job == 0) ? 1 : (job == 1) ? 0 : job;

  const float* hsrc = pot_old + (hk * NB + b) * NPTS;
  const float* fold_src = pot_old + (job * NB + b) * NPTS;
  float* fdst = pot_new + (job * NB + b) * NPTS;
  const float2* colp = cols + b * NPTS;
  const float2* rowp = rows + b * NPTS;

  // stage columns + h into LDS, track max(h)
  float lmax = -1e30f;
  for (int j = tid; j < NPTS; j += BLOCK) {
    float2 c = colp[j];
    float h = fmaf(hsrc[j], inv_eps, base);
    ys[j] = c;
    hs[j] = h;
    lmax = fmaxf(lmax, h);
  }
  for (int o = 32; o; o >>= 1) lmax = fmaxf(lmax, __shfl_xor(lmax, o, 64));
  if (lane == 0) redm[wave] = lmax;
  __syncthreads();
  const float M = fmaxf(fmaxf(redm[0], redm[1]), fmaxf(redm[2], redm[3]));
  for (int j = tid; j < NPTS; j += BLOCK) hs[j] = (hs[j] - M) * LOG2E;  // own elems, RAW same-thread
  __syncthreads();

  const int row0 = chunk * ROWS_PER_CHUNK + wave * 4;
  const float2 xi0 = rowp[row0 + 0];
  const float2 xi1 = rowp[row0 + 1];
  const float2 xi2 = rowp[row0 + 2];
  const float2 xi3 = rowp[row0 + 3];
  float s0 = 0.0f, s1 = 0.0f, s2 = 0.0f, s3 = 0.0f;

#pragma unroll 4
  for (int jj = 0; jj < NPTS / 64; jj++) {
    const int j = (jj << 6) | lane;
    const float2 yj = ys[j];
    const float hh = hs[j];
    float dx, dy, d2;
    dx = xi0.x - yj.x; dy = xi0.y - yj.y;
    d2 = fmaxf(fmaf(dx, dx, dy * dy), 1e-12f);
    s0 += EXP2F(fmaf(FSQRTF(d2), -ce, hh));
    dx = xi1.x - yj.x; dy = xi1.y - yj.y;
    d2 = fmaxf(fmaf(dx, dx, dy * dy), 1e-12f);
    s1 += EXP2F(fmaf(FSQRTF(d2), -ce, hh));
    dx = xi2.x - yj.x; dy = xi2.y - yj.y;
    d2 = fmaxf(fmaf(dx, dx, dy * dy), 1e-12f);
    s2 += EXP2F(fmaf(FSQRTF(d2), -ce, hh));
    dx = xi3.x - yj.x; dy = xi3.y - yj.y;
    d2 = fmaxf(fmaf(dx, dx, dy * dy), 1e-12f);
    s3 += EXP2F(fmaf(FSQRTF(d2), -ce, hh));
  }

  for (int o = 32; o; o >>= 1) {
    s0 += __shfl_xor(s0, o, 64);
    s1 += __shfl_xor(s1, o, 64);
    s2 += __shfl_xor(s2, o, 64);
    s3 += __shfl_xor(s3, o, 64);
  }
  if (lane == 0) {
    float sv[4] = {s0, s1, s2, s3};
#pragma unroll
    for (int q = 0; q < 4; q++) {
      float s = fmaxf(sv[q], 1e-37f);  // insurance vs full-row underflow
      float ft = -eps * fmaf(0.69314718055994531f, LOG2F(s), M);
      float fo = fold_src[row0 + q];
      float fn = (wmix >= 1.0f) ? fo : fmaf(wmix, fo, (1.0f - wmix) * ft);
      fdst[row0 + q] = fn;
    }
  }
}

// ---------------------------------------------------------------------------
// Kernel C: out = mean_b [ (1/N) sum(f_ba - f_aa) + (1/M) sum(g_ab - g_bb) ]
// ---------------------------------------------------------------------------
__global__ __launch_bounds__(BLOCK) void k_reduce(
    const float* __restrict__ pot, float* __restrict__ out)
{
  const int tid = threadIdx.x;
  double acc = 0.0;
  for (int i = tid; i < POT_SZ; i += BLOCK) {
    double v = (double)pot[i];
    acc += (i < 2 * NB * NPTS) ? v : -v;  // +f_ba +g_ab -f_aa -g_bb
  }
  for (int o = 32; o; o >>= 1) acc += __shfl_xor(acc, o, 64);
  __shared__ double rd[4];
  const int wave = tid >> 6, lane = tid & 63;
  if (lane == 0) rd[wave] = acc;
  __syncthreads();
  if (tid == 0) out[0] = (float)((rd[0] + rd[1] + rd[2] + rd[3]) / (double)(NB * NPTS));
}

extern "C" void kernel_launch(void* const* d_in, const int* in_sizes, int n_in,
                              void* d_out, int out_size, void* d_ws, size_t ws_size,
                              hipStream_t stream)
{
  const float2* x = (const float2*)d_in[0];  // pre (2,4096,2)
  const float2* y = (const float2*)d_in[1];  // gt  (2,4096,2)
  float* ws = (float*)d_ws;
  float* sched = ws + SCHED_OFF;
  float* pot0 = ws + POT0_OFF;
  float* pot1 = pot0 + POT_SZ;

  k_schedule<<<1, BLOCK, 0, stream>>>(x, y, ws);

  dim3 grid(NPTS / ROWS_PER_CHUNK, NB, 4);
  for (int s = 0; s < K_TOTAL; s++) {
    const float* po = (s & 1) ? pot1 : pot0;
    float* pn = (s & 1) ? pot0 : pot1;
    k_softmin<<<grid, BLOCK, 0, stream>>>(x, y, sched, po, pn, s);
  }
  // K_TOTAL even -> final potentials land in pot0
  k_reduce<<<1, BLOCK, 0, stream>>>(pot0, (float*)d_out);
}

// Round 3
// 534.028 us; speedup vs baseline: 1.7315x; 1.2083x over previous
//
#include <hip/hip_runtime.h>
#include <math.h>

#define NPTS 4096
#define NB 2
#define K_TOTAL 12
#define BLOCK 256
#define TILE 128
#define NT (NPTS / TILE)   // 32 tile-blocks per dimension

// ws layout (floats):
//  [0..24)        sched: 12 x {eps, w}
//  [32..40)       Mbuf: per (pot,batch) running max of h
//  [64..)         P: 4 pots x NB x NPTS   (f_ba, g_ab, f_aa, g_bb)
//  [..)           V: exp((h - M)*log2e) per source pot
//  [..)           S: row-sum accumulators per pot
#define SCHED_OFF 0
#define MBUF_OFF 32
#define P_OFF 64
#define POT_SZ (4 * NB * NPTS)
#define V_OFF (P_OFF + POT_SZ)
#define S_OFF (V_OFF + POT_SZ)

#if __has_builtin(__builtin_amdgcn_exp2f)
#define EXP2F __builtin_amdgcn_exp2f
#else
#define EXP2F exp2f
#endif
#if __has_builtin(__builtin_amdgcn_logf)
#define LOG2F __builtin_amdgcn_logf
#else
#define LOG2F log2f
#endif
#if __has_builtin(__builtin_amdgcn_sqrtf)
#define FSQRTF __builtin_amdgcn_sqrtf
#else
#define FSQRTF sqrtf
#endif

#define BASE_LOGW -8.31776616671934f  // -log(4096), N==M
#define LOG2E 1.4426950408889634f
#define LN2 0.69314718055994531f

// ---------------------------------------------------------------------------
// Kernel A: zero P/S, V=1, Mbuf=base (h = logw + 0/eps). Diameter (f32,
// matching numpy) + eps schedule (f64, matching np.arange/np.exp).
// ---------------------------------------------------------------------------
__global__ __launch_bounds__(BLOCK) void k_init(
    const float2* __restrict__ x, const float2* __restrict__ y, float* ws)
{
  const int tid = threadIdx.x;
  for (int i = tid; i < POT_SZ; i += BLOCK) {
    ws[P_OFF + i] = 0.0f;
    ws[S_OFF + i] = 0.0f;
    ws[V_OFF + i] = 1.0f;
  }
  if (tid < 8) ws[MBUF_OFF + tid] = BASE_LOGW;

  float mnx = 1e30f, mny = 1e30f, mxx = -1e30f, mxy = -1e30f;
  for (int i = tid; i < NB * NPTS; i += BLOCK) {
    float2 p = x[i];
    mnx = fminf(mnx, p.x); mxx = fmaxf(mxx, p.x);
    mny = fminf(mny, p.y); mxy = fmaxf(mxy, p.y);
    float2 q = y[i];
    mnx = fminf(mnx, q.x); mxx = fmaxf(mxx, q.x);
    mny = fminf(mny, q.y); mxy = fmaxf(mxy, q.y);
  }
  for (int o = 32; o; o >>= 1) {
    mnx = fminf(mnx, __shfl_xor(mnx, o, 64));
    mxx = fmaxf(mxx, __shfl_xor(mxx, o, 64));
    mny = fminf(mny, __shfl_xor(mny, o, 64));
    mxy = fmaxf(mxy, __shfl_xor(mxy, o, 64));
  }
  __shared__ float r[4][4];
  const int wave = tid >> 6, lane = tid & 63;
  if (lane == 0) { r[0][wave] = mnx; r[1][wave] = mxx; r[2][wave] = mny; r[3][wave] = mxy; }
  __syncthreads();
  if (tid == 0) {
    mnx = fminf(fminf(r[0][0], r[0][1]), fminf(r[0][2], r[0][3]));
    mxx = fmaxf(fmaxf(r[1][0], r[1][1]), fmaxf(r[1][2], r[1][3]));
    mny = fminf(fminf(r[2][0], r[2][1]), fminf(r[2][2], r[2][3]));
    mxy = fmaxf(fmaxf(r[3][0], r[3][1]), fmaxf(r[3][2], r[3][3]));
    float rx = mxx - mnx, ry = mxy - mny;
    float dia = sqrtf(rx * rx + ry * ry);

    double a = log((double)dia);
    double stop = log(0.05);
    double stp = log(0.5);
    int cnt = (int)ceil((stop - a) / stp);  // data: cnt == 8
    if (cnt < 0) cnt = 0;
    if (cnt > K_TOTAL - 4) cnt = K_TOTAL - 4;

    float* sch = ws + SCHED_OFF;
    sch[0] = dia; sch[1] = 0.0f;   // init: direct assign at eps=diameter
    sch[2] = dia; sch[3] = 0.5f;   // loop over eps_list, w=0.5
    for (int k = 0; k < cnt; k++) {
      sch[2 * (2 + k)] = (float)exp(a + (double)k * stp);
      sch[2 * (2 + k) + 1] = 0.5f;
    }
    sch[2 * (2 + cnt)] = 0.05f; sch[2 * (2 + cnt) + 1] = 0.5f;
    for (int s = 3 + cnt; s < K_TOTAL - 1; s++) { sch[2 * s] = 0.05f; sch[2 * s + 1] = 1.0f; }
    sch[2 * (K_TOTAL - 1)] = 0.05f; sch[2 * (K_TOTAL - 1) + 1] = 0.0f;  // final extrapolation
  }
}

// ---------------------------------------------------------------------------
// Kernel B: K-tile sweep. Each block owns a 128x128 tile of one cost matrix,
// computes K_ij = exp2(-c_ij * ce) ONCE, and accumulates BOTH row sums
// (S_row += K . Vcol) and column sums (S_col += K^T . Vrow):
//  - cross tiles (C_xy): rows feed S0 (f_ba) via V1, cols feed S1 (g_ab)
//    via V0 -- one sqrt+exp serves two potentials.
//  - self tiles (C_xx / C_yy, symmetric): only ti<=tj computed; off-diagonal
//    tiles contribute to rows ti and rows tj of the same S.
// blocks: [0, 2048) cross; [2048, 6144) self (ti>tj blocks exit early).
// ---------------------------------------------------------------------------
__global__ __launch_bounds__(BLOCK, 4) void k_tiles(
    const float2* __restrict__ xpts, const float2* __restrict__ ypts,
    float* __restrict__ ws, int stepi)
{
  __shared__ float rXs[TILE], rYs[TILE], rVs[TILE];
  __shared__ float cXs[TILE], cYs[TILE], cVs[TILE];
  __shared__ float rowPart[16][132];
  __shared__ float colPart[16][132];

  const int tid = threadIdx.x;
  const int id = blockIdx.x;

  const float2* rowp; const float2* colp;
  const float* vrow; const float* vcol;
  float* srow; float* scol;
  int ti, tj;
  bool dual;

  if (id < NB * NT * NT) {
    const int b = id >> 10;
    const int t = id & (NT * NT - 1);
    ti = t >> 5; tj = t & (NT - 1);
    rowp = xpts + b * NPTS; colp = ypts + b * NPTS;
    vrow = ws + V_OFF + (0 * NB + b) * NPTS;  // V built from P0=f_ba
    vcol = ws + V_OFF + (1 * NB + b) * NPTS;  // V built from P1=g_ab
    srow = ws + S_OFF + (0 * NB + b) * NPTS;  // row sums -> new f_ba
    scol = ws + S_OFF + (1 * NB + b) * NPTS;  // col sums -> new g_ab
    dual = true;
  } else {
    const int id2 = id - NB * NT * NT;
    const int mat = id2 >> 11;      // 0: C_xx, 1: C_yy  (NB*NT*NT == 2048)
    const int t2 = id2 & 2047;
    const int b = t2 >> 10;
    const int t = t2 & 1023;
    ti = t >> 5; tj = t & 31;
    if (ti > tj) return;            // symmetric: upper triangle only
    const float2* pts = mat ? ypts : xpts;
    rowp = pts + b * NPTS; colp = rowp;
    const int p = 2 + mat;
    vrow = ws + V_OFF + (p * NB + b) * NPTS;
    vcol = vrow;
    srow = ws + S_OFF + (p * NB + b) * NPTS;
    scol = srow;
    dual = (ti != tj);              // diagonal tile: row sums only
  }

  const float eps = ws[SCHED_OFF + 2 * stepi];
  const float nce = -LOG2E / eps;

  if (tid < TILE) {
    float2 pr = rowp[ti * TILE + tid];
    rXs[tid] = pr.x; rYs[tid] = pr.y;
    rVs[tid] = vrow[ti * TILE + tid];
  } else {
    const int k = tid - TILE;
    float2 pc = colp[tj * TILE + k];
    cXs[k] = pc.x; cYs[k] = pc.y;
    cVs[k] = vcol[tj * TILE + k];
  }
  __syncthreads();

  const int tx = tid & 15, ty = tid >> 4;
  float rx[8], ry[8], rv[8], cx[8], cy[8], cv[8], racc[8], cacc[8];
#pragma unroll
  for (int q = 0; q < 8; q++) {
    rx[q] = rXs[ty * 8 + q]; ry[q] = rYs[ty * 8 + q]; rv[q] = rVs[ty * 8 + q];
    cx[q] = cXs[tx * 8 + q]; cy[q] = cYs[tx * 8 + q]; cv[q] = cVs[tx * 8 + q];
    racc[q] = 0.0f; cacc[q] = 0.0f;
  }

#pragma unroll
  for (int q = 0; q < 8; q++) {
#pragma unroll
    for (int p = 0; p < 8; p++) {
      float dx = rx[q] - cx[p];
      float dy = ry[q] - cy[p];
      float d2 = fmaxf(fmaf(dx, dx, dy * dy), 1e-12f);
      float K = EXP2F(FSQRTF(d2) * nce);
      racc[q] = fmaf(K, cv[p], racc[q]);
      cacc[p] = fmaf(K, rv[q], cacc[p]);
    }
  }

#pragma unroll
  for (int q = 0; q < 8; q++) {
    rowPart[tx][ty * 8 + q] = racc[q];
    colPart[ty][tx * 8 + q] = cacc[q];
  }
  __syncthreads();

  if (tid < TILE) {
    float s = 0.0f;
#pragma unroll
    for (int t = 0; t < 16; t++) s += rowPart[t][tid];
    atomicAdd(&srow[ti * TILE + tid], s);
  } else if (dual) {
    const int k = tid - TILE;
    float s = 0.0f;
#pragma unroll
    for (int t = 0; t < 16; t++) s += colPart[t][k];
    atomicAdd(&scol[tj * TILE + k], s);
  }
}

// ---------------------------------------------------------------------------
// Kernel C: per (pot,batch): finalize f from S, mix with w, write P in place;
// build next step's V = exp2((logw + P/eps_next - Mnew)*log2e); zero S.
// ---------------------------------------------------------------------------
__global__ __launch_bounds__(BLOCK) void k_combine(float* __restrict__ ws, int stepi)
{
  const int pb = blockIdx.x;
  const int p = pb >> 1, b = pb & 1;
  const int tid = threadIdx.x;

  const float eps = ws[SCHED_OFF + 2 * stepi];
  const float w = ws[SCHED_OFF + 2 * stepi + 1];
  int ni = stepi + 1; if (ni > K_TOTAL - 1) ni = K_TOTAL - 1;
  const float inv_eps_n = 1.0f / ws[SCHED_OFF + 2 * ni];
  const float Mh = ws[MBUF_OFF + pb];

  float* Pp = ws + P_OFF + (p * NB + b) * NPTS;
  float* Vp = ws + V_OFF + (p * NB + b) * NPTS;
  float* Sp = ws + S_OFF + (p * NB + b) * NPTS;

  float h[16];
  float lmax = -1e30f;
#pragma unroll
  for (int q = 0; q < 16; q++) {
    const int r = q * BLOCK + tid;
    float s = fmaxf(Sp[r], 1e-37f);
    float ft = -eps * fmaf(LN2, LOG2F(s), Mh);
    float fo = Pp[r];
    float fn = (w >= 1.0f) ? fo : fmaf(w, fo, (1.0f - w) * ft);
    Pp[r] = fn;
    Sp[r] = 0.0f;
    h[q] = fmaf(fn, inv_eps_n, BASE_LOGW);
    lmax = fmaxf(lmax, h[q]);
  }
  for (int o = 32; o; o >>= 1) lmax = fmaxf(lmax, __shfl_xor(lmax, o, 64));
  __shared__ float red[4];
  if ((tid & 63) == 0) red[tid >> 6] = lmax;
  __syncthreads();
  const float M = fmaxf(fmaxf(red[0], red[1]), fmaxf(red[2], red[3]));
#pragma unroll
  for (int q = 0; q < 16; q++) {
    const int r = q * BLOCK + tid;
    Vp[r] = EXP2F((h[q] - M) * LOG2E);
  }
  if (tid == 0) ws[MBUF_OFF + pb] = M;
}

// ---------------------------------------------------------------------------
// Kernel D: out = mean_b [ (1/N) sum(f_ba - f_aa) + (1/M) sum(g_ab - g_bb) ]
// ---------------------------------------------------------------------------
__global__ __launch_bounds__(BLOCK) void k_reduce(
    const float* __restrict__ pot, float* __restrict__ out)
{
  const int tid = threadIdx.x;
  double acc = 0.0;
  for (int i = tid; i < POT_SZ; i += BLOCK) {
    double v = (double)pot[i];
    acc += (i < 2 * NB * NPTS) ? v : -v;  // +f_ba +g_ab -f_aa -g_bb
  }
  for (int o = 32; o; o >>= 1) acc += __shfl_xor(acc, o, 64);
  __shared__ double rd[4];
  const int wave = tid >> 6, lane = tid & 63;
  if (lane == 0) rd[wave] = acc;
  __syncthreads();
  if (tid == 0) out[0] = (float)((rd[0] + rd[1] + rd[2] + rd[3]) / (double)(NB * NPTS));
}

extern "C" void kernel_launch(void* const* d_in, const int* in_sizes, int n_in,
                              void* d_out, int out_size, void* d_ws, size_t ws_size,
                              hipStream_t stream)
{
  const float2* x = (const float2*)d_in[0];  // pre (2,4096,2)
  const float2* y = (const float2*)d_in[1];  // gt  (2,4096,2)
  float* ws = (float*)d_ws;

  k_init<<<1, BLOCK, 0, stream>>>(x, y, ws);

  const int nblocks = NB * NT * NT + 2 * NB * NT * NT;  // 2048 cross + 4096 self
  for (int s = 0; s < K_TOTAL; s++) {
    k_tiles<<<nblocks, BLOCK, 0, stream>>>(x, y, ws, s);
    k_combine<<<8, BLOCK, 0, stream>>>(ws, s);
  }
  k_reduce<<<1, BLOCK, 0, stream>>>(ws + P_OFF, (float*)d_out);
}